// Round 1
// baseline (335.202 us; speedup 1.0000x reference)
//
#include <hip/hip_runtime.h>

// Policy net: GRU(64 steps) -> id-embed/comm-mean concat -> 8-agent attention -> MLP heads.
// K1: one wave = 32 sequences, fused K=96 MFMA per step (h|x|bias), no barriers.
// K2: one WG = 8 batches (64 agents), fully fused heads in LDS.

typedef float f32x4 __attribute__((ext_vector_type(4)));
typedef short bf16x8 __attribute__((ext_vector_type(8)));

#define MFMA16 __builtin_amdgcn_mfma_f32_16x16x32_bf16
#define LOG2E 1.44269504088896f
#define INV_SQRT_D 0.09449111825230679f

__device__ __forceinline__ short f2bf(float f) {
    union { float f; unsigned u; } v; v.f = f;
    unsigned r = v.u + 0x7fffu + ((v.u >> 16) & 1u);   // RNE, finite inputs only
    return (short)(r >> 16);
}
__device__ __forceinline__ float fexp2(float x) { return __builtin_amdgcn_exp2f(x); }
__device__ __forceinline__ float frcp(float x)  { return __builtin_amdgcn_rcpf(x); }

// ---------------------------------------------------------------------------
// Kernel 1: GRU. grid 256 x 256 threads -> 1024 waves x 32 seqs = 32768 seqs.
// ---------------------------------------------------------------------------
__global__ __launch_bounds__(256, 1) void gru_kernel(
    const float* __restrict__ seq,    // [32768][64][4] (raw reshape: 256 floats/seq)
    const float* __restrict__ W_ih,   // [192][4]
    const float* __restrict__ W_hh,   // [192][64]
    const float* __restrict__ b_ih,   // [192]
    const float* __restrict__ b_hh,   // [192]
    unsigned short* __restrict__ h_out) // [32768][64] bf16
{
    __shared__ short hlds[4][32][72];   // per-wave h transpose buffer (+8 pad vs bank conflicts)
    const int tid  = threadIdx.x;
    const int wave = tid >> 6;
    const int lane = tid & 63;
    const int l15  = lane & 15;
    const int q    = lane >> 4;
    const int seqbase = (blockIdx.x * 4 + wave) * 32;
    short (*hl)[72] = hlds[wave];

    {   // zero this wave's LDS slice (wave-local, no barrier needed)
        int* p = (int*)&hl[0][0];
        #pragma unroll
        for (int i = 0; i < 18; ++i) p[lane + 64 * i] = 0;
    }

    // ---- preload B fragments: B[k][n] held as W[row g][k0..k0+7], n = l15 within tile ----
    bf16x8 Bh[12][2];   // W_hh, K-chunks 0,1 (k=0..63)
    bf16x8 B2[12];      // chunk2: [W_ih | combined bias] (r,z) or [bias only] (n-tiles)
    bf16x8 B2x[4];      // chunk2 for separate xn accumulator: [W_ih_n | b_ih_n]
    #pragma unroll
    for (int j = 0; j < 12; ++j) {
        int g = j * 16 + l15;
        #pragma unroll
        for (int c = 0; c < 2; ++c) {
            const float* wp = W_hh + g * 64 + c * 32 + q * 8;
            bf16x8 f;
            #pragma unroll
            for (int u = 0; u < 8; ++u) f[u] = f2bf(wp[u]);
            Bh[j][c] = f;
        }
        bf16x8 f2 = {0,0,0,0,0,0,0,0};
        if (q == 0) {
            if (g < 128) {   // r,z gates: x-proj weights + (b_ih + b_hh)
                #pragma unroll
                for (int u = 0; u < 4; ++u) f2[u] = f2bf(W_ih[g * 4 + u]);
                f2[4] = f2bf(b_ih[g] + b_hh[g]);
            } else {         // hn accumulator: only b_hh (b_ih_n lives in xn path)
                f2[4] = f2bf(b_hh[g]);
            }
        }
        B2[j] = f2;
    }
    #pragma unroll
    for (int j2 = 0; j2 < 4; ++j2) {
        int g = 128 + j2 * 16 + l15;
        bf16x8 f = {0,0,0,0,0,0,0,0};
        if (q == 0) {
            #pragma unroll
            for (int u = 0; u < 4; ++u) f[u] = f2bf(W_ih[g * 4 + u]);
            f[4] = f2bf(b_ih[g]);
        }
        B2x[j2] = f;
    }

    const short onebf = 0x3f80;  // bf16 1.0
    float h[2][4][4];
    #pragma unroll
    for (int rt = 0; rt < 2; ++rt)
        #pragma unroll
        for (int j = 0; j < 4; ++j)
            #pragma unroll
            for (int r = 0; r < 4; ++r) h[rt][j][r] = 0.f;

    f32x4 xc[2];
    #pragma unroll
    for (int rt = 0; rt < 2; ++rt)
        xc[rt] = *(const f32x4*)(seq + (size_t)(seqbase + 16 * rt + l15) * 256);

    const f32x4 zz = {0.f, 0.f, 0.f, 0.f};

    for (int t = 0; t < 64; ++t) {
        f32x4 xnext[2];
        if (t < 63) {   // prefetch next timestep's x
            #pragma unroll
            for (int rt = 0; rt < 2; ++rt)
                xnext[rt] = *(const f32x4*)(seq + (size_t)(seqbase + 16 * rt + l15) * 256 + (t + 1) * 4);
        }

        bf16x8 A0[2], A1[2], A2[2];
        #pragma unroll
        for (int rt = 0; rt < 2; ++rt) {
            A0[rt] = *(const bf16x8*)&hl[16 * rt + l15][q * 8];        // h, k 0..31
            A1[rt] = *(const bf16x8*)&hl[16 * rt + l15][32 + q * 8];   // h, k 32..63
            bf16x8 a2;
            a2[0] = f2bf(xc[rt][0]); a2[1] = f2bf(xc[rt][1]);
            a2[2] = f2bf(xc[rt][2]); a2[3] = f2bf(xc[rt][3]);
            a2[4] = onebf; a2[5] = 0; a2[6] = 0; a2[7] = 0;            // [x|1|0..], only q0 matters
            A2[rt] = a2;
        }

        f32x4 acc[2][12], accx[2][4];
        #pragma unroll
        for (int rt = 0; rt < 2; ++rt) {
            #pragma unroll
            for (int j = 0; j < 12; ++j) {
                f32x4 a = MFMA16(A2[rt], B2[j], zz, 0, 0, 0);
                a = MFMA16(A0[rt], Bh[j][0], a, 0, 0, 0);
                a = MFMA16(A1[rt], Bh[j][1], a, 0, 0, 0);
                acc[rt][j] = a;
            }
            #pragma unroll
            for (int j2 = 0; j2 < 4; ++j2)
                accx[rt][j2] = MFMA16(A2[rt], B2x[j2], zz, 0, 0, 0);
        }

        // gates: element (rt, j, r) -> seq row 16rt+q*4+r, channel c = 16j+l15
        #pragma unroll
        for (int rt = 0; rt < 2; ++rt) {
            #pragma unroll
            for (int j = 0; j < 4; ++j) {
                #pragma unroll
                for (int r = 0; r < 4; ++r) {
                    float ar = acc[rt][j][r];
                    float az = acc[rt][4 + j][r];
                    float hn = acc[rt][8 + j][r];
                    float xn = accx[rt][j][r];
                    float rg = frcp(1.f + fexp2(-LOG2E * ar));
                    float zg = frcp(1.f + fexp2(-LOG2E * az));
                    float npre = fmaf(rg, hn, xn);
                    float ng = 1.f - 2.f * frcp(1.f + fexp2(2.f * LOG2E * npre)); // tanh
                    float hv = h[rt][j][r];
                    float hnew = fmaf(zg, hv - ng, ng);   // (1-z)n + z h
                    h[rt][j][r] = hnew;
                    hl[16 * rt + q * 4 + r][16 * j + l15] = f2bf(hnew);
                }
            }
        }
        if (t < 63) { xc[0] = xnext[0]; xc[1] = xnext[1]; }
    }

    #pragma unroll
    for (int rt = 0; rt < 2; ++rt)
        #pragma unroll
        for (int j = 0; j < 4; ++j)
            #pragma unroll
            for (int r = 0; r < 4; ++r)
                h_out[(size_t)(seqbase + 16 * rt + q * 4 + r) * 64 + 16 * j + l15] =
                    (unsigned short)f2bf(h[rt][j][r]);
}

// ---------------------------------------------------------------------------
// Kernel 2: heads. grid 512 x 256 threads; WG = 8 batches = 64 agents.
// ---------------------------------------------------------------------------
__global__ __launch_bounds__(256, 1) void head_kernel(
    const unsigned short* __restrict__ hseq,  // [32768][64] bf16
    const float* __restrict__ embed,
    const float* __restrict__ Wm, const float* __restrict__ bm,
    const float* __restrict__ Wq, const float* __restrict__ bq,
    const float* __restrict__ Wk, const float* __restrict__ bk,
    const float* __restrict__ Wv, const float* __restrict__ bv,
    const float* __restrict__ W1, const float* __restrict__ b1,
    const float* __restrict__ W2, const float* __restrict__ b2,
    const float* __restrict__ Wmean, const float* __restrict__ bmean,
    const float* __restrict__ Wval, const float* __restrict__ bval,
    float* __restrict__ out)                  // mean [32768][2] then val [32768]
{
    __shared__ short hcat[64][136];  // [h(64) | id(16) | c(32) | 0-pad]
    __shared__ short Qb[64][136];
    __shared__ short Kb[64][136];
    __shared__ short Ob[64][136];
    __shared__ short h3b[64][136];
    __shared__ short h4b[64][136];
    __shared__ short Vt[112][80];    // V transposed: [Dcol][agent]
    __shared__ short Pb[64][40];     // attention probs, A-layout rows
    __shared__ float msgs[64][36];
    __shared__ float cmean[8][32];

    const int tid = threadIdx.x;
    const int w   = tid >> 6;
    const int lane = tid & 63;
    const int l15 = lane & 15;
    const int q   = lane >> 4;
    const int agent0 = blockIdx.x * 64;
    const f32x4 zz4 = {0.f, 0.f, 0.f, 0.f};

    {   // zero all bf16 LDS (pads must be 0 for padded-K MFMAs)
        int* p;
        p = (int*)&hcat[0][0]; for (int i = tid; i < 4352; i += 256) p[i] = 0;
        p = (int*)&Qb[0][0];   for (int i = tid; i < 4352; i += 256) p[i] = 0;
        p = (int*)&Kb[0][0];   for (int i = tid; i < 4352; i += 256) p[i] = 0;
        p = (int*)&Ob[0][0];   for (int i = tid; i < 4352; i += 256) p[i] = 0;
        p = (int*)&h3b[0][0];  for (int i = tid; i < 4352; i += 256) p[i] = 0;
        p = (int*)&h4b[0][0];  for (int i = tid; i < 4352; i += 256) p[i] = 0;
        p = (int*)&Vt[0][0];   for (int i = tid; i < 4480; i += 256) p[i] = 0;
        p = (int*)&Pb[0][0];   for (int i = tid; i < 1280; i += 256) p[i] = 0;
    }
    __syncthreads();

    // P0: stage h + id embedding
    for (int i = tid; i < 512; i += 256) {
        int row = i >> 3, part = i & 7;
        *(bf16x8*)&hcat[row][part * 8] =
            *(const bf16x8*)(hseq + (size_t)(agent0 + row) * 64 + part * 8);
    }
    for (int i = tid; i < 1024; i += 256) {
        int row = i >> 4, e = i & 15;
        hcat[row][64 + e] = f2bf(embed[(row & 7) * 16 + e]);
    }
    __syncthreads();

    // B-fragment from global fp32 weight W[nrows][Klim], zero beyond limits
    auto bfrag = [&](const float* W, int nrows, int Klim, int g, int k0) -> bf16x8 {
        bf16x8 f = {0,0,0,0,0,0,0,0};
        if (g < nrows && (k0 + 8) <= Klim) {
            const float* wp = W + (size_t)g * Klim + k0;
            f32x4 w0 = *(const f32x4*)wp;
            f32x4 w1 = *(const f32x4*)(wp + 4);
            f[0] = f2bf(w0[0]); f[1] = f2bf(w0[1]); f[2] = f2bf(w0[2]); f[3] = f2bf(w0[3]);
            f[4] = f2bf(w1[0]); f[5] = f2bf(w1[1]); f[6] = f2bf(w1[2]); f[7] = f2bf(w1[3]);
        }
        return f;
    };

    // P1: msgs = [h|id] @ Wm^T + bm   (K=80, hcat cols 80..95 still zero)
    #pragma unroll
    for (int ct = 0; ct < 2; ++ct) {
        f32x4 acc = zz4;
        #pragma unroll
        for (int ch = 0; ch < 3; ++ch) {
            bf16x8 a = *(const bf16x8*)&hcat[16 * w + l15][ch * 32 + q * 8];
            acc = MFMA16(a, bfrag(Wm, 32, 80, 16 * ct + l15, ch * 32 + q * 8), acc, 0, 0, 0);
        }
        float bias = bm[16 * ct + l15];
        #pragma unroll
        for (int r = 0; r < 4; ++r) msgs[16 * w + q * 4 + r][16 * ct + l15] = acc[r] + bias;
    }
    __syncthreads();

    // P2: per-batch mean over 8 agents, write into hcat cols 80..111
    {
        int b = tid >> 5, m = tid & 31;
        float s = 0.f;
        #pragma unroll
        for (int j = 0; j < 8; ++j) s += msgs[b * 8 + j][m];
        cmean[b][m] = 0.125f * s;
    }
    __syncthreads();
    for (int i = tid; i < 2048; i += 256) {
        int row = i >> 5, m = i & 31;
        hcat[row][80 + m] = f2bf(cmean[row >> 3][m]);
    }
    __syncthreads();

    // P3: Q,K,V = hcat @ W^T + b  (K=112 pad 128; Q pre-scaled by 1/sqrt(112))
    #pragma unroll
    for (int ct = 0; ct < 7; ++ct) {
        f32x4 aq = zz4, ak = zz4, av = zz4;
        #pragma unroll
        for (int ch = 0; ch < 4; ++ch) {
            bf16x8 a = *(const bf16x8*)&hcat[16 * w + l15][ch * 32 + q * 8];
            aq = MFMA16(a, bfrag(Wq, 112, 112, 16 * ct + l15, ch * 32 + q * 8), aq, 0, 0, 0);
            ak = MFMA16(a, bfrag(Wk, 112, 112, 16 * ct + l15, ch * 32 + q * 8), ak, 0, 0, 0);
            av = MFMA16(a, bfrag(Wv, 112, 112, 16 * ct + l15, ch * 32 + q * 8), av, 0, 0, 0);
        }
        int col = 16 * ct + l15;
        float biq = bq[col], bik = bk[col], biv = bv[col];
        #pragma unroll
        for (int r = 0; r < 4; ++r) {
            int row = 16 * w + q * 4 + r;
            Qb[row][col] = f2bf((aq[r] + biq) * INV_SQRT_D);
            Kb[row][col] = f2bf(ak[r] + bik);
            Vt[col][row] = f2bf(av[r] + biv);
        }
    }
    __syncthreads();

    // P4: S = Q K^T (diagonal 16x16 tile = 2 batches), in-register 8-wide softmax
    {
        f32x4 acc = zz4;
        #pragma unroll
        for (int ch = 0; ch < 4; ++ch) {
            bf16x8 a = *(const bf16x8*)&Qb[16 * w + l15][ch * 32 + q * 8];
            bf16x8 b = *(const bf16x8*)&Kb[16 * w + l15][ch * 32 + q * 8];
            acc = MFMA16(a, b, acc, 0, 0, 0);
        }
        bool collow = (l15 < 8);
        #pragma unroll
        for (int r = 0; r < 4; ++r) {
            int rl = q * 4 + r;
            bool valid = ((rl < 8) == collow);   // block-diagonal mask
            float v = acc[r];
            float m = v;
            m = fmaxf(m, __shfl_xor(m, 1, 64));
            m = fmaxf(m, __shfl_xor(m, 2, 64));
            m = fmaxf(m, __shfl_xor(m, 4, 64));
            float e = fexp2(LOG2E * (v - m));
            float s = e;
            s += __shfl_xor(s, 1, 64);
            s += __shfl_xor(s, 2, 64);
            s += __shfl_xor(s, 4, 64);
            float pv = valid ? e * frcp(s) : 0.f;
            Pb[16 * w + rl][l15] = f2bf(pv);
        }
    }
    __syncthreads();

    // P5: O = P V  (K=32, P cols 16..31 zero)
    #pragma unroll
    for (int ct = 0; ct < 7; ++ct) {
        bf16x8 a = *(const bf16x8*)&Pb[16 * w + l15][q * 8];
        bf16x8 b = *(const bf16x8*)&Vt[16 * ct + l15][16 * w + q * 8];
        f32x4 acc = MFMA16(a, b, zz4, 0, 0, 0);
        #pragma unroll
        for (int r = 0; r < 4; ++r) Ob[16 * w + q * 4 + r][16 * ct + l15] = f2bf(acc[r]);
    }
    __syncthreads();

    // P6: h3 = relu(O @ W1^T + b1)   K=112 pad 128, N=128
    #pragma unroll
    for (int ct = 0; ct < 8; ++ct) {
        f32x4 acc = zz4;
        #pragma unroll
        for (int ch = 0; ch < 4; ++ch) {
            bf16x8 a = *(const bf16x8*)&Ob[16 * w + l15][ch * 32 + q * 8];
            acc = MFMA16(a, bfrag(W1, 128, 112, 16 * ct + l15, ch * 32 + q * 8), acc, 0, 0, 0);
        }
        float bias = b1[16 * ct + l15];
        #pragma unroll
        for (int r = 0; r < 4; ++r)
            h3b[16 * w + q * 4 + r][16 * ct + l15] = f2bf(fmaxf(acc[r] + bias, 0.f));
    }
    __syncthreads();

    // P7: h4 = relu(h3 @ W2^T + b2)  K=128, N=128
    #pragma unroll
    for (int ct = 0; ct < 8; ++ct) {
        f32x4 acc = zz4;
        #pragma unroll
        for (int ch = 0; ch < 4; ++ch) {
            bf16x8 a = *(const bf16x8*)&h3b[16 * w + l15][ch * 32 + q * 8];
            acc = MFMA16(a, bfrag(W2, 128, 128, 16 * ct + l15, ch * 32 + q * 8), acc, 0, 0, 0);
        }
        float bias = b2[16 * ct + l15];
        #pragma unroll
        for (int r = 0; r < 4; ++r)
            h4b[16 * w + q * 4 + r][16 * ct + l15] = f2bf(fmaxf(acc[r] + bias, 0.f));
    }
    __syncthreads();

    // P8: heads. B rows: n=0,1 -> Wmean rows; n=2 -> Wval; K=128
    {
        f32x4 acc = zz4;
        #pragma unroll
        for (int ch = 0; ch < 4; ++ch) {
            bf16x8 a = *(const bf16x8*)&h4b[16 * w + l15][ch * 32 + q * 8];
            int k0 = ch * 32 + q * 8;
            bf16x8 b = {0,0,0,0,0,0,0,0};
            const float* wp = nullptr;
            if (l15 == 0)      wp = Wmean + k0;
            else if (l15 == 1) wp = Wmean + 128 + k0;
            else if (l15 == 2) wp = Wval + k0;
            if (wp) {
                f32x4 w0 = *(const f32x4*)wp;
                f32x4 w1 = *(const f32x4*)(wp + 4);
                b[0] = f2bf(w0[0]); b[1] = f2bf(w0[1]); b[2] = f2bf(w0[2]); b[3] = f2bf(w0[3]);
                b[4] = f2bf(w1[0]); b[5] = f2bf(w1[1]); b[6] = f2bf(w1[2]); b[7] = f2bf(w1[3]);
            }
            acc = MFMA16(a, b, acc, 0, 0, 0);
        }
        if (l15 < 3) {
            float bias = (l15 == 0) ? bmean[0] : (l15 == 1) ? bmean[1] : bval[0];
            #pragma unroll
            for (int r = 0; r < 4; ++r) {
                int A = agent0 + 16 * w + q * 4 + r;
                float v = acc[r] + bias;
                if (l15 < 2) out[(size_t)A * 2 + l15] = v;     // mean [32768][2]
                else         out[65536 + A] = v;               // val  [32768]
            }
        }
    }
}

// ---------------------------------------------------------------------------
extern "C" void kernel_launch(void* const* d_in, const int* in_sizes, int n_in,
                              void* d_out, int out_size, void* d_ws, size_t ws_size,
                              hipStream_t stream) {
    const float* seq   = (const float*)d_in[0];
    const float* W_ih  = (const float*)d_in[1];
    const float* W_hh  = (const float*)d_in[2];
    const float* b_ih  = (const float*)d_in[3];
    const float* b_hh  = (const float*)d_in[4];
    const float* embed = (const float*)d_in[5];
    const float* Wm    = (const float*)d_in[6];
    const float* bm    = (const float*)d_in[7];
    const float* Wq    = (const float*)d_in[8];
    const float* bq    = (const float*)d_in[9];
    const float* Wk    = (const float*)d_in[10];
    const float* bk    = (const float*)d_in[11];
    const float* Wv    = (const float*)d_in[12];
    const float* bv    = (const float*)d_in[13];
    const float* W1    = (const float*)d_in[14];
    const float* b1    = (const float*)d_in[15];
    const float* W2    = (const float*)d_in[16];
    const float* b2    = (const float*)d_in[17];
    const float* Wmean = (const float*)d_in[18];
    const float* bmean = (const float*)d_in[19];
    const float* Wval  = (const float*)d_in[20];
    const float* bval  = (const float*)d_in[21];

    unsigned short* hbuf = (unsigned short*)d_ws;  // [32768][64] bf16 = 4 MB

    gru_kernel<<<256, 256, 0, stream>>>(seq, W_ih, W_hh, b_ih, b_hh, hbuf);
    head_kernel<<<512, 256, 0, stream>>>(hbuf, embed, Wm, bm, Wq, bq, Wk, bk, Wv, bv,
                                         W1, b1, W2, b2, Wmean, bmean, Wval, bval,
                                         (float*)d_out);
}

// Round 2
// 254.485 us; speedup vs baseline: 1.3172x; 1.3172x over previous
//
#include <hip/hip_runtime.h>

// Policy net: GRU(64 steps) -> id-embed/comm-mean concat -> 8-agent attention -> MLP heads.
// K0: one-time weight->bf16 MFMA-fragment conversion into d_ws.
// K1: GRU, one wave = 16 sequences, 2048 waves, 2 waves/SIMD, pre-scaled exp2 gates.
// K2: one WG = 8 batches (64 agents), fused heads in aliased LDS (75 KB -> 2 WG/CU).

typedef float f32x4 __attribute__((ext_vector_type(4)));
typedef short bf16x8 __attribute__((ext_vector_type(8)));

#define MFMA16 __builtin_amdgcn_mfma_f32_16x16x32_bf16
#define LOG2E 1.44269504088896f
#define INV_SQRT_D 0.09449111825230679f

__device__ __forceinline__ short f2bf(float f) {          // RNE (cold paths)
    union { float f; unsigned u; } v; v.f = f;
    unsigned r = v.u + 0x7fffu + ((v.u >> 16) & 1u);
    return (short)(r >> 16);
}
__device__ __forceinline__ short f2bf_hu(float f) {       // round-half-up (hot paths)
    union { float f; unsigned u; } v; v.f = f;
    return (short)((v.u + 0x8000u) >> 16);
}
__device__ __forceinline__ float fexp2(float x) { return __builtin_amdgcn_exp2f(x); }
__device__ __forceinline__ float frcp(float x)  { return __builtin_amdgcn_rcpf(x); }

// ---------------------------------------------------------------------------
// Kernel 0: convert head weights to bf16 B-fragments (MFMA lane layout).
// Fragment table (fid): 0..5 Wm(ct*3+ch) | 6..33 Wq | 34..61 Wk | 62..89 Wv |
//                       90..121 W1 | 122..153 W2 | 154..157 heads
// Fragment storage: wf[(fid*64 + lane)*8 .. +7]
// ---------------------------------------------------------------------------
__global__ void conv_kernel(
    const float* __restrict__ Wm, const float* __restrict__ Wq,
    const float* __restrict__ Wk, const float* __restrict__ Wv,
    const float* __restrict__ W1, const float* __restrict__ W2,
    const float* __restrict__ Wmean, const float* __restrict__ Wval,
    unsigned short* __restrict__ wf)
{
    int gid = blockIdx.x * 256 + threadIdx.x;
    if (gid >= 158 * 64) return;
    int fid = gid >> 6, lane = gid & 63;
    int l15 = lane & 15, q = lane >> 4;

    short out[8] = {0,0,0,0,0,0,0,0};
    if (fid < 154) {
        const float* W; int nrows, Klim, idx;
        if (fid < 6)        { W = Wm; nrows = 32;  Klim = 80;  idx = fid;       }
        else if (fid < 34)  { W = Wq; nrows = 112; Klim = 112; idx = fid - 6;   }
        else if (fid < 62)  { W = Wk; nrows = 112; Klim = 112; idx = fid - 34;  }
        else if (fid < 90)  { W = Wv; nrows = 112; Klim = 112; idx = fid - 62;  }
        else if (fid < 122) { W = W1; nrows = 128; Klim = 112; idx = fid - 90;  }
        else                { W = W2; nrows = 128; Klim = 128; idx = fid - 122; }
        int nch = (fid < 6) ? 3 : 4;
        int ct = idx / nch, ch = idx - ct * nch;
        int g = ct * 16 + l15, k0 = ch * 32 + q * 8;
        if (g < nrows && (k0 + 8) <= Klim) {
            const float* wp = W + (size_t)g * Klim + k0;
            #pragma unroll
            for (int u = 0; u < 8; ++u) out[u] = f2bf(wp[u]);
        }
    } else {
        int ch = fid - 154, k0 = ch * 32 + q * 8;   // Klim=128, all k valid
        const float* wp = (l15 == 0) ? Wmean : (l15 == 1) ? (Wmean + 128)
                          : (l15 == 2) ? Wval : nullptr;
        if (wp) {
            #pragma unroll
            for (int u = 0; u < 8; ++u) out[u] = f2bf(wp[k0 + u]);
        }
    }
    *(bf16x8*)(wf + ((size_t)fid * 64 + lane) * 8) = *(bf16x8*)out;
}

// ---------------------------------------------------------------------------
// Kernel 1: GRU. grid 512 x 256 -> 2048 waves x 16 seqs = 32768 seqs.
// Weights pre-scaled: rows 0..127 (r,z) by -log2e, rows 128..191 (n) by 2*log2e,
// so gate exps are exp2(acc) directly.
// ---------------------------------------------------------------------------
__global__ __launch_bounds__(256, 2) void gru_kernel(
    const float* __restrict__ seq,    // [32768][64][4]
    const float* __restrict__ W_ih,   // [192][4]
    const float* __restrict__ W_hh,   // [192][64]
    const float* __restrict__ b_ih,
    const float* __restrict__ b_hh,
    unsigned short* __restrict__ h_out) // [32768][64] bf16
{
    __shared__ short hlds[4][16][72];
    const int tid  = threadIdx.x;
    const int wave = tid >> 6;
    const int lane = tid & 63;
    const int l15  = lane & 15;
    const int q    = lane >> 4;
    const int seqbase = (blockIdx.x * 4 + wave) * 16;
    short (*hl)[72] = hlds[wave];

    {   // zero this wave's LDS slice (wave-local, no barrier)
        int* p = (int*)&hl[0][0];
        #pragma unroll
        for (int i = 0; i < 9; ++i) p[lane + 64 * i] = 0;
    }

    const float sc_rz = -LOG2E;
    const float sc_n  = 2.0f * LOG2E;

    // B fragments: B[k][n], lane holds W[row g = tile*16+l15][k = q*8+u]
    bf16x8 Bh[12][2];   // W_hh k-chunks 0,1
    bf16x8 B2[12];      // chunk2: [W_ih | bias] (q==0 lanes only)
    bf16x8 B2x[4];      // chunk2 for xn accumulator
    #pragma unroll
    for (int j = 0; j < 12; ++j) {
        int g = j * 16 + l15;
        float s = (j < 8) ? sc_rz : sc_n;
        #pragma unroll
        for (int c = 0; c < 2; ++c) {
            const float* wp = W_hh + g * 64 + c * 32 + q * 8;
            bf16x8 f;
            #pragma unroll
            for (int u = 0; u < 8; ++u) f[u] = f2bf(wp[u] * s);
            Bh[j][c] = f;
        }
        bf16x8 f2 = {0,0,0,0,0,0,0,0};
        if (q == 0) {
            if (j < 8) {
                #pragma unroll
                for (int u = 0; u < 4; ++u) f2[u] = f2bf(W_ih[g * 4 + u] * s);
                f2[4] = f2bf((b_ih[g] + b_hh[g]) * s);
            } else {
                f2[4] = f2bf(b_hh[g] * s);
            }
        }
        B2[j] = f2;
    }
    #pragma unroll
    for (int j2 = 0; j2 < 4; ++j2) {
        int g = 128 + j2 * 16 + l15;
        bf16x8 f = {0,0,0,0,0,0,0,0};
        if (q == 0) {
            #pragma unroll
            for (int u = 0; u < 4; ++u) f[u] = f2bf(W_ih[g * 4 + u] * sc_n);
            f[4] = f2bf(b_ih[g] * sc_n);
        }
        B2x[j2] = f;
    }

    const short onebf = 0x3f80;
    float h[4][4];
    #pragma unroll
    for (int j = 0; j < 4; ++j)
        #pragma unroll
        for (int r = 0; r < 4; ++r) h[j][r] = 0.f;

    f32x4 xc = *(const f32x4*)(seq + (size_t)(seqbase + l15) * 256);
    const f32x4 zz = {0.f, 0.f, 0.f, 0.f};

    for (int t = 0; t < 64; ++t) {
        f32x4 xnext;
        if (t < 63)
            xnext = *(const f32x4*)(seq + (size_t)(seqbase + l15) * 256 + (t + 1) * 4);

        bf16x8 A0 = *(const bf16x8*)&hl[l15][q * 8];        // h, k 0..31
        bf16x8 A1 = *(const bf16x8*)&hl[l15][32 + q * 8];   // h, k 32..63
        bf16x8 A2;
        A2[0] = f2bf_hu(xc[0]); A2[1] = f2bf_hu(xc[1]);
        A2[2] = f2bf_hu(xc[2]); A2[3] = f2bf_hu(xc[3]);
        A2[4] = onebf; A2[5] = 0; A2[6] = 0; A2[7] = 0;     // only q0 k-slots matter

        #pragma unroll
        for (int j = 0; j < 4; ++j) {
            f32x4 ar = MFMA16(A2, B2[j], zz, 0, 0, 0);
            ar = MFMA16(A0, Bh[j][0], ar, 0, 0, 0);
            ar = MFMA16(A1, Bh[j][1], ar, 0, 0, 0);
            f32x4 az = MFMA16(A2, B2[4 + j], zz, 0, 0, 0);
            az = MFMA16(A0, Bh[4 + j][0], az, 0, 0, 0);
            az = MFMA16(A1, Bh[4 + j][1], az, 0, 0, 0);
            f32x4 an = MFMA16(A2, B2[8 + j], zz, 0, 0, 0);
            an = MFMA16(A0, Bh[8 + j][0], an, 0, 0, 0);
            an = MFMA16(A1, Bh[8 + j][1], an, 0, 0, 0);
            f32x4 ax = MFMA16(A2, B2x[j], zz, 0, 0, 0);

            #pragma unroll
            for (int r = 0; r < 4; ++r) {
                float e_r  = fexp2(ar[r]);                  // exp(-pre_r)
                float rg   = frcp(1.f + e_r);
                float e_z  = fexp2(az[r]);                  // exp(-pre_z)
                float npre = fmaf(rg, an[r], ax[r]);        // 2*log2e*(xn + r*hn)
                float e_t  = fexp2(npre);                   // exp(2*npre_orig)
                float tp   = e_t + 1.f;
                float tm   = e_t - 1.f;
                float hv   = h[j][r];
                float num  = fmaf(hv, tp, e_z * tm);
                float den  = tp * (1.f + e_z);
                float hnew = num * frcp(den);
                h[j][r] = hnew;
                hl[q * 4 + r][16 * j + l15] = f2bf_hu(hnew);
            }
        }
        if (t < 63) xc = xnext;
    }

    #pragma unroll
    for (int j = 0; j < 4; ++j)
        #pragma unroll
        for (int r = 0; r < 4; ++r)
            h_out[(size_t)(seqbase + q * 4 + r) * 64 + 16 * j + l15] =
                (unsigned short)f2bf_hu(h[j][r]);
}

// ---------------------------------------------------------------------------
// Kernel 2: heads. grid 512 x 256; WG = 8 batches (64 agents). 2 WG/CU.
// LDS aliasing: R1 = hcat -> Ob | R2 = Qb -> h3b | R3 = msgs -> Kb -> h4b
//               Vt standalone | Pb (cmean overlay early)
// ---------------------------------------------------------------------------
__global__ __launch_bounds__(256, 2) void head_kernel(
    const unsigned short* __restrict__ hseq,  // [32768][64] bf16
    const unsigned short* __restrict__ wf,    // fragment table
    const float* __restrict__ embed,
    const float* __restrict__ bm, const float* __restrict__ bq,
    const float* __restrict__ bk, const float* __restrict__ bv,
    const float* __restrict__ b1, const float* __restrict__ b2,
    const float* __restrict__ bmean, const float* __restrict__ bval,
    float* __restrict__ out)                  // mean [32768][2] then val [32768]
{
    __shared__ short R1[64][136];   // hcat (h|id|c|pad0) -> Ob
    __shared__ short R2[64][136];   // Qb -> h3b
    __shared__ short R3[64][136];   // msgs overlay -> Kb -> h4b
    __shared__ short Vt[112][80];   // V^T: [Dcol][agent]
    __shared__ short Pb[64][40];    // cmean overlay -> attention probs

    float (*msgs)[33]  = (float(*)[33])&R3[0][0];   // 64x33 f32 = 8448 B
    float (*cmean)[32] = (float(*)[32])&Pb[0][0];   // 8x32 f32 = 1024 B

    const int tid  = threadIdx.x;
    const int w    = tid >> 6;
    const int lane = tid & 63;
    const int l15  = lane & 15;
    const int q    = lane >> 4;
    const int agent0 = blockIdx.x * 64;
    const f32x4 zz4 = {0.f, 0.f, 0.f, 0.f};

    auto ld = [&](int fid) -> bf16x8 {
        return *(const bf16x8*)(wf + ((size_t)fid * 64 + lane) * 8);
    };

    {   // init zero: R1 full, R2 full, Vt full, Pb full
        int* p;
        p = (int*)&R1[0][0]; for (int i = tid; i < 4352; i += 256) p[i] = 0;
        p = (int*)&R2[0][0]; for (int i = tid; i < 4352; i += 256) p[i] = 0;
        p = (int*)&Vt[0][0]; for (int i = tid; i < 4480; i += 256) p[i] = 0;
        p = (int*)&Pb[0][0]; for (int i = tid; i < 1280; i += 256) p[i] = 0;
    }
    __syncthreads();

    // P0: stage h + id embedding into R1
    for (int i = tid; i < 512; i += 256) {
        int row = i >> 3, part = i & 7;
        *(bf16x8*)&R1[row][part * 8] =
            *(const bf16x8*)(hseq + (size_t)(agent0 + row) * 64 + part * 8);
    }
    for (int i = tid; i < 1024; i += 256) {
        int row = i >> 4, e = i & 15;
        R1[row][64 + e] = f2bf(embed[(row & 7) * 16 + e]);
    }
    __syncthreads();

    // P1: msgs = [h|id] @ Wm^T + bm  (K=80; R1 cols 80..95 are zero)
    #pragma unroll
    for (int ct = 0; ct < 2; ++ct) {
        f32x4 acc = zz4;
        #pragma unroll
        for (int ch = 0; ch < 3; ++ch) {
            bf16x8 a = *(const bf16x8*)&R1[16 * w + l15][ch * 32 + q * 8];
            acc = MFMA16(a, ld(ct * 3 + ch), acc, 0, 0, 0);
        }
        float bias = bm[16 * ct + l15];
        #pragma unroll
        for (int r = 0; r < 4; ++r) msgs[16 * w + q * 4 + r][16 * ct + l15] = acc[r] + bias;
    }
    __syncthreads();

    // P2: per-batch mean over 8 agents -> cmean -> R1 cols 80..111
    {
        int b = tid >> 5, m = tid & 31;
        float s = 0.f;
        #pragma unroll
        for (int j = 0; j < 8; ++j) s += msgs[b * 8 + j][m];
        cmean[b][m] = 0.125f * s;
    }
    __syncthreads();
    for (int i = tid; i < 2048; i += 256) {
        int row = i >> 5, m = i & 31;
        R1[row][80 + m] = f2bf_hu(cmean[row >> 3][m]);
    }
    __syncthreads();

    // P3: Q,K,V (K=112 pad 128). Also re-zero pads trashed by overlays:
    //     R3 cols 112..127 (msgs) and Pb cols 16..39 (cmean).
    for (int i = tid; i < 512; i += 256) {          // 64 rows x 8 int
        int row = i >> 3, cp = i & 7;
        *(int*)&R3[row][112 + cp * 2] = 0;
    }
    for (int i = tid; i < 768; i += 256) {          // 64 rows x 12 int
        int row = i / 12, cp = i - row * 12;
        *(int*)&Pb[row][16 + cp * 2] = 0;
    }
    #pragma unroll
    for (int ct = 0; ct < 7; ++ct) {
        f32x4 aq = zz4, ak = zz4, av = zz4;
        #pragma unroll
        for (int ch = 0; ch < 4; ++ch) {
            bf16x8 a = *(const bf16x8*)&R1[16 * w + l15][ch * 32 + q * 8];
            aq = MFMA16(a, ld(6  + ct * 4 + ch), aq, 0, 0, 0);
            ak = MFMA16(a, ld(34 + ct * 4 + ch), ak, 0, 0, 0);
            av = MFMA16(a, ld(62 + ct * 4 + ch), av, 0, 0, 0);
        }
        int col = 16 * ct + l15;
        float biq = bq[col], bik = bk[col], biv = bv[col];
        #pragma unroll
        for (int r = 0; r < 4; ++r) {
            int row = 16 * w + q * 4 + r;
            R2[row][col] = f2bf_hu((aq[r] + biq) * INV_SQRT_D);
            R3[row][col] = f2bf_hu(ak[r] + bik);
            Vt[col][row] = f2bf_hu(av[r] + biv);
        }
    }
    __syncthreads();

    // P4: S = Q K^T diagonal tile; 8-wide in-register softmax; mask off-batch
    {
        f32x4 acc = zz4;
        #pragma unroll
        for (int ch = 0; ch < 4; ++ch) {
            bf16x8 a = *(const bf16x8*)&R2[16 * w + l15][ch * 32 + q * 8];
            bf16x8 b = *(const bf16x8*)&R3[16 * w + l15][ch * 32 + q * 8];
            acc = MFMA16(a, b, acc, 0, 0, 0);
        }
        bool collow = (l15 < 8);
        #pragma unroll
        for (int r = 0; r < 4; ++r) {
            int rl = q * 4 + r;
            bool valid = ((rl < 8) == collow);
            float v = acc[r];
            float m = v;
            m = fmaxf(m, __shfl_xor(m, 1, 64));
            m = fmaxf(m, __shfl_xor(m, 2, 64));
            m = fmaxf(m, __shfl_xor(m, 4, 64));
            float e = fexp2(LOG2E * (v - m));
            float s = e;
            s += __shfl_xor(s, 1, 64);
            s += __shfl_xor(s, 2, 64);
            s += __shfl_xor(s, 4, 64);
            float pv = valid ? e * frcp(s) : 0.f;
            Pb[16 * w + rl][l15] = f2bf_hu(pv);
        }
    }
    __syncthreads();

    // P5: O = P V  (K=32, Pb cols 16..31 zero) -> R1 (pads still pristine zero)
    #pragma unroll
    for (int ct = 0; ct < 7; ++ct) {
        bf16x8 a = *(const bf16x8*)&Pb[16 * w + l15][q * 8];
        bf16x8 b = *(const bf16x8*)&Vt[16 * ct + l15][16 * w + q * 8];
        f32x4 acc = MFMA16(a, b, zz4, 0, 0, 0);
        #pragma unroll
        for (int r = 0; r < 4; ++r) R1[16 * w + q * 4 + r][16 * ct + l15] = f2bf_hu(acc[r]);
    }
    __syncthreads();

    // P6: h3 = relu(O @ W1^T + b1)  K=112 pad 128 -> R2
    #pragma unroll
    for (int ct = 0; ct < 8; ++ct) {
        f32x4 acc = zz4;
        #pragma unroll
        for (int ch = 0; ch < 4; ++ch) {
            bf16x8 a = *(const bf16x8*)&R1[16 * w + l15][ch * 32 + q * 8];
            acc = MFMA16(a, ld(90 + ct * 4 + ch), acc, 0, 0, 0);
        }
        float bias = b1[16 * ct + l15];
        #pragma unroll
        for (int r = 0; r < 4; ++r)
            R2[16 * w + q * 4 + r][16 * ct + l15] = f2bf_hu(fmaxf(acc[r] + bias, 0.f));
    }
    __syncthreads();

    // P7: h4 = relu(h3 @ W2^T + b2)  K=128 -> R3
    #pragma unroll
    for (int ct = 0; ct < 8; ++ct) {
        f32x4 acc = zz4;
        #pragma unroll
        for (int ch = 0; ch < 4; ++ch) {
            bf16x8 a = *(const bf16x8*)&R2[16 * w + l15][ch * 32 + q * 8];
            acc = MFMA16(a, ld(122 + ct * 4 + ch), acc, 0, 0, 0);
        }
        float bias = b2[16 * ct + l15];
        #pragma unroll
        for (int r = 0; r < 4; ++r)
            R3[16 * w + q * 4 + r][16 * ct + l15] = f2bf_hu(fmaxf(acc[r] + bias, 0.f));
    }
    __syncthreads();

    // P8: heads (K=128): cols 0,1 -> mean; col 2 -> value
    {
        f32x4 acc = zz4;
        #pragma unroll
        for (int ch = 0; ch < 4; ++ch) {
            bf16x8 a = *(const bf16x8*)&R3[16 * w + l15][ch * 32 + q * 8];
            acc = MFMA16(a, ld(154 + ch), acc, 0, 0, 0);
        }
        if (l15 < 3) {
            float bias = (l15 == 0) ? bmean[0] : (l15 == 1) ? bmean[1] : bval[0];
            #pragma unroll
            for (int r = 0; r < 4; ++r) {
                int A = agent0 + 16 * w + q * 4 + r;
                float v = acc[r] + bias;
                if (l15 < 2) out[(size_t)A * 2 + l15] = v;
                else         out[65536 + A] = v;
            }
        }
    }
}

// ---------------------------------------------------------------------------
extern "C" void kernel_launch(void* const* d_in, const int* in_sizes, int n_in,
                              void* d_out, int out_size, void* d_ws, size_t ws_size,
                              hipStream_t stream) {
    const float* seq   = (const float*)d_in[0];
    const float* W_ih  = (const float*)d_in[1];
    const float* W_hh  = (const float*)d_in[2];
    const float* b_ih  = (const float*)d_in[3];
    const float* b_hh  = (const float*)d_in[4];
    const float* embed = (const float*)d_in[5];
    const float* Wm    = (const float*)d_in[6];
    const float* bm    = (const float*)d_in[7];
    const float* Wq    = (const float*)d_in[8];
    const float* bq    = (const float*)d_in[9];
    const float* Wk    = (const float*)d_in[10];
    const float* bk    = (const float*)d_in[11];
    const float* Wv    = (const float*)d_in[12];
    const float* bv    = (const float*)d_in[13];
    const float* W1    = (const float*)d_in[14];
    const float* b1    = (const float*)d_in[15];
    const float* W2    = (const float*)d_in[16];
    const float* b2    = (const float*)d_in[17];
    const float* Wmean = (const float*)d_in[18];
    const float* bmean = (const float*)d_in[19];
    const float* Wval  = (const float*)d_in[20];
    const float* bval  = (const float*)d_in[21];

    unsigned short* hbuf = (unsigned short*)d_ws;        // [32768][64] bf16 = 4 MB
    unsigned short* wf   = hbuf + (size_t)32768 * 64;    // 158 frags * 64 * 8 shorts

    conv_kernel<<<40, 256, 0, stream>>>(Wm, Wq, Wk, Wv, W1, W2, Wmean, Wval, wf);
    gru_kernel<<<512, 256, 0, stream>>>(seq, W_ih, W_hh, b_ih, b_hh, hbuf);
    head_kernel<<<512, 256, 0, stream>>>(hbuf, wf, embed, bm, bq, bk, bv,
                                         b1, b2, bmean, bval, (float*)d_out);
}

// Round 3
// 249.013 us; speedup vs baseline: 1.3461x; 1.0220x over previous
//
#include <hip/hip_runtime.h>

// Policy net fully fused: GRU(64 steps) -> comm-mean -> 8-agent attention -> MLP heads.
// K0: one-time weight->bf16 MFMA-fragment conversion into d_ws.
// K1: one wave = 16 seqs = 2 complete batches; GRU + ALL head phases wave-local
//     (zero __syncthreads; LDS slices are per-wave). 2048 waves, 2 waves/SIMD.

typedef float f32x4 __attribute__((ext_vector_type(4)));
typedef short bf16x8 __attribute__((ext_vector_type(8)));

#define MFMA16 __builtin_amdgcn_mfma_f32_16x16x32_bf16
#define LOG2E 1.44269504088896f
#define INV_SQRT_D 0.09449111825230679f

__device__ __forceinline__ short f2bf(float f) {          // RNE (cold paths)
    union { float f; unsigned u; } v; v.f = f;
    unsigned r = v.u + 0x7fffu + ((v.u >> 16) & 1u);
    return (short)(r >> 16);
}
__device__ __forceinline__ short f2bf_hu(float f) {       // round-half-up (hot paths)
    union { float f; unsigned u; } v; v.f = f;
    return (short)((v.u + 0x8000u) >> 16);
}
__device__ __forceinline__ float fexp2(float x) { return __builtin_amdgcn_exp2f(x); }
__device__ __forceinline__ float frcp(float x)  { return __builtin_amdgcn_rcpf(x); }
__device__ __forceinline__ void lds_fence() {             // cross-lane LDS RAW guard
    __asm__ __volatile__("s_waitcnt lgkmcnt(0)" ::: "memory");
}

// ---------------------------------------------------------------------------
// Kernel 0: head weights -> bf16 B-fragments (MFMA lane layout).
// fid: 0..5 Wm | 6..33 Wq | 34..61 Wk | 62..89 Wv | 90..121 W1 | 122..153 W2 |
//      154..157 heads.  Storage: wf[(fid*64+lane)*8 .. +7]
// ---------------------------------------------------------------------------
__global__ void conv_kernel(
    const float* __restrict__ Wm, const float* __restrict__ Wq,
    const float* __restrict__ Wk, const float* __restrict__ Wv,
    const float* __restrict__ W1, const float* __restrict__ W2,
    const float* __restrict__ Wmean, const float* __restrict__ Wval,
    unsigned short* __restrict__ wf)
{
    int gid = blockIdx.x * 256 + threadIdx.x;
    if (gid >= 158 * 64) return;
    int fid = gid >> 6, lane = gid & 63;
    int l15 = lane & 15, q = lane >> 4;

    short out[8] = {0,0,0,0,0,0,0,0};
    if (fid < 154) {
        const float* W; int nrows, Klim, idx;
        if (fid < 6)        { W = Wm; nrows = 32;  Klim = 80;  idx = fid;       }
        else if (fid < 34)  { W = Wq; nrows = 112; Klim = 112; idx = fid - 6;   }
        else if (fid < 62)  { W = Wk; nrows = 112; Klim = 112; idx = fid - 34;  }
        else if (fid < 90)  { W = Wv; nrows = 112; Klim = 112; idx = fid - 62;  }
        else if (fid < 122) { W = W1; nrows = 128; Klim = 112; idx = fid - 90;  }
        else                { W = W2; nrows = 128; Klim = 128; idx = fid - 122; }
        int nch = (fid < 6) ? 3 : 4;
        int ct = idx / nch, ch = idx - ct * nch;
        int g = ct * 16 + l15, k0 = ch * 32 + q * 8;
        if (g < nrows && (k0 + 8) <= Klim) {
            const float* wp = W + (size_t)g * Klim + k0;
            #pragma unroll
            for (int u = 0; u < 8; ++u) out[u] = f2bf(wp[u]);
        }
    } else {
        int ch = fid - 154, k0 = ch * 32 + (lane >> 4) * 8;
        const float* wp = (l15 == 0) ? Wmean : (l15 == 1) ? (Wmean + 128)
                          : (l15 == 2) ? Wval : nullptr;
        if (wp) {
            #pragma unroll
            for (int u = 0; u < 8; ++u) out[u] = f2bf(wp[k0 + u]);
        }
    }
    *(bf16x8*)(wf + ((size_t)fid * 64 + lane) * 8) = *(bf16x8*)out;
}

// ---------------------------------------------------------------------------
// Kernel 1: fused policy. grid 512 x 256 -> 2048 waves x 16 seqs.
// ---------------------------------------------------------------------------
__global__ __launch_bounds__(256, 2) void policy_kernel(
    const float* __restrict__ seq,    // [32768][64][4]
    const float* __restrict__ W_ih, const float* __restrict__ W_hh,
    const float* __restrict__ b_ih, const float* __restrict__ b_hh,
    const float* __restrict__ embed,
    const unsigned short* __restrict__ wf,
    const float* __restrict__ bm, const float* __restrict__ bq,
    const float* __restrict__ bk, const float* __restrict__ bv,
    const float* __restrict__ b1, const float* __restrict__ b2,
    const float* __restrict__ bmean, const float* __restrict__ bval,
    float* __restrict__ out)          // mean [32768][2] then val [32768]
{
    __shared__ short R1s[4][16][136];  // h(0..63)|id(64..79)|c(80..111)|pad -> O
    __shared__ short R2s[4][16][136];  // Q -> h3
    __shared__ short R3s[4][16][136];  // K -> h4
    __shared__ short Vts[4][114][20];  // V^T [Dcol][agent], zero-padded
    __shared__ short Pbs[4][16][40];   // attention probs (A-layout rows)

    const int tid  = threadIdx.x;
    const int wv   = tid >> 6;
    const int lane = tid & 63;
    const int l15  = lane & 15;
    const int q    = lane >> 4;
    const int seqbase = (blockIdx.x * 4 + wv) * 16;   // 16 seqs = batches 2w,2w+1

    short (*R1)[136] = R1s[wv];
    short (*R2)[136] = R2s[wv];
    short (*R3)[136] = R3s[wv];
    short (*Vt)[20]  = Vts[wv];
    short (*Pb)[40]  = Pbs[wv];
    const f32x4 zz = {0.f, 0.f, 0.f, 0.f};

    {   // zero this wave's LDS slices (wave-local)
        int* p;
        p = (int*)&R1[0][0]; for (int i = lane; i < 1088; i += 64) p[i] = 0;
        p = (int*)&R2[0][0]; for (int i = lane; i < 1088; i += 64) p[i] = 0;
        p = (int*)&R3[0][0]; for (int i = lane; i < 1088; i += 64) p[i] = 0;
        p = (int*)&Vt[0][0]; for (int i = lane; i < 1140; i += 64) p[i] = 0;
        p = (int*)&Pb[0][0]; for (int i = lane; i < 320;  i += 64) p[i] = 0;
    }
    {   // id embedding -> R1 cols 64..79 (agent row i uses embed[i&7])
        int row = lane >> 2, j0 = (lane & 3) * 4;
        f32x4 e = *(const f32x4*)(embed + (row & 7) * 16 + j0);
        #pragma unroll
        for (int u = 0; u < 4; ++u) R1[row][64 + j0 + u] = f2bf(e[u]);
    }

    // ---- GRU weight fragments (pre-scaled so exps are exp2(acc) directly) ----
    const float sc_rz = -LOG2E;
    const float sc_n  = 2.0f * LOG2E;
    bf16x8 Bh[12][2], B2[12], B2x[4];
    #pragma unroll
    for (int j = 0; j < 12; ++j) {
        int g = j * 16 + l15;
        float s = (j < 8) ? sc_rz : sc_n;
        #pragma unroll
        for (int c = 0; c < 2; ++c) {
            const float* wp = W_hh + g * 64 + c * 32 + q * 8;
            bf16x8 f;
            #pragma unroll
            for (int u = 0; u < 8; ++u) f[u] = f2bf(wp[u] * s);
            Bh[j][c] = f;
        }
        bf16x8 f2 = {0,0,0,0,0,0,0,0};
        if (q == 0) {
            if (j < 8) {
                #pragma unroll
                for (int u = 0; u < 4; ++u) f2[u] = f2bf(W_ih[g * 4 + u] * s);
                f2[4] = f2bf((b_ih[g] + b_hh[g]) * s);
            } else {
                f2[4] = f2bf(b_hh[g] * s);
            }
        }
        B2[j] = f2;
    }
    #pragma unroll
    for (int j2 = 0; j2 < 4; ++j2) {
        int g = 128 + j2 * 16 + l15;
        bf16x8 f = {0,0,0,0,0,0,0,0};
        if (q == 0) {
            #pragma unroll
            for (int u = 0; u < 4; ++u) f[u] = f2bf(W_ih[g * 4 + u] * sc_n);
            f[4] = f2bf(b_ih[g] * sc_n);
        }
        B2x[j2] = f;
    }
    lds_fence();

    // ---- GRU main loop: h lives in R1 cols 0..63 ----
    const short onebf = 0x3f80;
    float h[4][4];
    #pragma unroll
    for (int j = 0; j < 4; ++j)
        #pragma unroll
        for (int r = 0; r < 4; ++r) h[j][r] = 0.f;

    f32x4 xc = *(const f32x4*)(seq + (size_t)(seqbase + l15) * 256);

    for (int t = 0; t < 64; ++t) {
        f32x4 xnext;
        if (t < 63)
            xnext = *(const f32x4*)(seq + (size_t)(seqbase + l15) * 256 + (t + 1) * 4);

        bf16x8 A0 = *(const bf16x8*)&R1[l15][q * 8];
        bf16x8 A1 = *(const bf16x8*)&R1[l15][32 + q * 8];
        bf16x8 A2;
        A2[0] = f2bf_hu(xc[0]); A2[1] = f2bf_hu(xc[1]);
        A2[2] = f2bf_hu(xc[2]); A2[3] = f2bf_hu(xc[3]);
        A2[4] = onebf; A2[5] = 0; A2[6] = 0; A2[7] = 0;

        #pragma unroll
        for (int j = 0; j < 4; ++j) {
            f32x4 ar = MFMA16(A2, B2[j], zz, 0, 0, 0);
            ar = MFMA16(A0, Bh[j][0], ar, 0, 0, 0);
            ar = MFMA16(A1, Bh[j][1], ar, 0, 0, 0);
            f32x4 az = MFMA16(A2, B2[4 + j], zz, 0, 0, 0);
            az = MFMA16(A0, Bh[4 + j][0], az, 0, 0, 0);
            az = MFMA16(A1, Bh[4 + j][1], az, 0, 0, 0);
            f32x4 an = MFMA16(A2, B2[8 + j], zz, 0, 0, 0);
            an = MFMA16(A0, Bh[8 + j][0], an, 0, 0, 0);
            an = MFMA16(A1, Bh[8 + j][1], an, 0, 0, 0);
            f32x4 ax = MFMA16(A2, B2x[j], zz, 0, 0, 0);

            #pragma unroll
            for (int r = 0; r < 4; ++r) {
                float e_r  = fexp2(ar[r]);
                float rg   = frcp(1.f + e_r);
                float e_z  = fexp2(az[r]);
                float npre = fmaf(rg, an[r], ax[r]);
                float e_t  = fexp2(npre);
                float tp   = e_t + 1.f;
                float tm   = e_t - 1.f;
                float hv   = h[j][r];
                float num  = fmaf(hv, tp, e_z * tm);
                float den  = tp * (1.f + e_z);
                float hnew = num * frcp(den);
                h[j][r] = hnew;
                R1[q * 4 + r][16 * j + l15] = f2bf_hu(hnew);
            }
        }
        if (t < 63) xc = xnext;
    }
    lds_fence();

    // ---- head phases, all wave-local ----
    auto ld = [&](int fid) -> bf16x8 {
        return *(const bf16x8*)(wf + ((size_t)fid * 64 + lane) * 8);
    };

    // P1+P2: msgs = [h|id] @ Wm^T ; comm mean over own batch; c -> R1 cols 80..111
    #pragma unroll
    for (int ct = 0; ct < 2; ++ct) {
        f32x4 acc = zz;
        #pragma unroll
        for (int ch = 0; ch < 3; ++ch) {
            bf16x8 a = *(const bf16x8*)&R1[l15][ch * 32 + q * 8];
            acc = MFMA16(a, ld(ct * 3 + ch), acc, 0, 0, 0);
        }
        float s = acc[0] + acc[1] + acc[2] + acc[3];   // rows q*4..q*4+3
        s += __shfl_xor(s, 16, 64);                    // + other q of same batch
        float cv = 0.125f * s + bm[16 * ct + l15];
        short cb = f2bf_hu(cv);
        #pragma unroll
        for (int r = 0; r < 4; ++r) R1[q * 4 + r][80 + 16 * ct + l15] = cb;
    }
    lds_fence();

    // P3: Q,K,V (K=112 pad 128); Q pre-scaled; V stored transposed
    #pragma unroll
    for (int ct = 0; ct < 7; ++ct) {
        f32x4 aq = zz, ak = zz, av = zz;
        #pragma unroll
        for (int ch = 0; ch < 4; ++ch) {
            bf16x8 a = *(const bf16x8*)&R1[l15][ch * 32 + q * 8];
            aq = MFMA16(a, ld(6  + ct * 4 + ch), aq, 0, 0, 0);
            ak = MFMA16(a, ld(34 + ct * 4 + ch), ak, 0, 0, 0);
            av = MFMA16(a, ld(62 + ct * 4 + ch), av, 0, 0, 0);
        }
        int col = 16 * ct + l15;
        float biq = bq[col], bik = bk[col], biv = bv[col];
        #pragma unroll
        for (int r = 0; r < 4; ++r) {
            int row = q * 4 + r;
            R2[row][col] = f2bf_hu((aq[r] + biq) * INV_SQRT_D);
            R3[row][col] = f2bf_hu(ak[r] + bik);
            Vt[col][row] = f2bf_hu(av[r] + biv);
        }
    }
    lds_fence();

    // P4: S = Q K^T (16x16 = 2 batches block-diagonal); 8-wide softmax via shfl
    {
        f32x4 acc = zz;
        #pragma unroll
        for (int ch = 0; ch < 4; ++ch) {
            bf16x8 a = *(const bf16x8*)&R2[l15][ch * 32 + q * 8];
            bf16x8 b = *(const bf16x8*)&R3[l15][ch * 32 + q * 8];
            acc = MFMA16(a, b, acc, 0, 0, 0);
        }
        bool collow = (l15 < 8);
        #pragma unroll
        for (int r = 0; r < 4; ++r) {
            int rl = q * 4 + r;
            bool valid = ((rl < 8) == collow);
            float v = acc[r];
            float m = v;
            m = fmaxf(m, __shfl_xor(m, 1, 64));
            m = fmaxf(m, __shfl_xor(m, 2, 64));
            m = fmaxf(m, __shfl_xor(m, 4, 64));
            float e = fexp2(LOG2E * (v - m));
            float s = e;
            s += __shfl_xor(s, 1, 64);
            s += __shfl_xor(s, 2, 64);
            s += __shfl_xor(s, 4, 64);
            float pv = valid ? e * frcp(s) : 0.f;
            Pb[rl][l15] = f2bf_hu(pv);
        }
    }
    lds_fence();

    // P5: O = P V (K=32; P cols 16..31 zero so Vt garbage-K is harmless) -> R1
    {
        bf16x8 a = *(const bf16x8*)&Pb[l15][q * 8];
        #pragma unroll
        for (int ct = 0; ct < 7; ++ct) {
            bf16x8 b = *(const bf16x8*)&Vt[16 * ct + l15][q * 8];
            f32x4 acc = MFMA16(a, b, zz, 0, 0, 0);
            #pragma unroll
            for (int r = 0; r < 4; ++r) R1[q * 4 + r][16 * ct + l15] = f2bf_hu(acc[r]);
        }
    }
    lds_fence();

    // P6: h3 = relu(O @ W1^T + b1)  K=112 pad 128 -> R2
    #pragma unroll
    for (int ct = 0; ct < 8; ++ct) {
        f32x4 acc = zz;
        #pragma unroll
        for (int ch = 0; ch < 4; ++ch) {
            bf16x8 a = *(const bf16x8*)&R1[l15][ch * 32 + q * 8];
            acc = MFMA16(a, ld(90 + ct * 4 + ch), acc, 0, 0, 0);
        }
        float bias = b1[16 * ct + l15];
        #pragma unroll
        for (int r = 0; r < 4; ++r)
            R2[q * 4 + r][16 * ct + l15] = f2bf_hu(fmaxf(acc[r] + bias, 0.f));
    }
    lds_fence();

    // P7: h4 = relu(h3 @ W2^T + b2)  K=128 -> R3
    #pragma unroll
    for (int ct = 0; ct < 8; ++ct) {
        f32x4 acc = zz;
        #pragma unroll
        for (int ch = 0; ch < 4; ++ch) {
            bf16x8 a = *(const bf16x8*)&R2[l15][ch * 32 + q * 8];
            acc = MFMA16(a, ld(122 + ct * 4 + ch), acc, 0, 0, 0);
        }
        float bias = b2[16 * ct + l15];
        #pragma unroll
        for (int r = 0; r < 4; ++r)
            R3[q * 4 + r][16 * ct + l15] = f2bf_hu(fmaxf(acc[r] + bias, 0.f));
    }
    lds_fence();

    // P8: heads (K=128): cols 0,1 -> mean; col 2 -> value
    {
        f32x4 acc = zz;
        #pragma unroll
        for (int ch = 0; ch < 4; ++ch) {
            bf16x8 a = *(const bf16x8*)&R3[l15][ch * 32 + q * 8];
            acc = MFMA16(a, ld(154 + ch), acc, 0, 0, 0);
        }
        if (l15 < 3) {
            float bias = (l15 == 0) ? bmean[0] : (l15 == 1) ? bmean[1] : bval[0];
            #pragma unroll
            for (int r = 0; r < 4; ++r) {
                int A = seqbase + q * 4 + r;
                float v = acc[r] + bias;
                if (l15 < 2) out[(size_t)A * 2 + l15] = v;
                else         out[65536 + A] = v;
            }
        }
    }
}

// ---------------------------------------------------------------------------
extern "C" void kernel_launch(void* const* d_in, const int* in_sizes, int n_in,
                              void* d_out, int out_size, void* d_ws, size_t ws_size,
                              hipStream_t stream) {
    const float* seq   = (const float*)d_in[0];
    const float* W_ih  = (const float*)d_in[1];
    const float* W_hh  = (const float*)d_in[2];
    const float* b_ih  = (const float*)d_in[3];
    const float* b_hh  = (const float*)d_in[4];
    const float* embed = (const float*)d_in[5];
    const float* Wm    = (const float*)d_in[6];
    const float* bm    = (const float*)d_in[7];
    const float* Wq    = (const float*)d_in[8];
    const float* bq    = (const float*)d_in[9];
    const float* Wk    = (const float*)d_in[10];
    const float* bk    = (const float*)d_in[11];
    const float* Wv    = (const float*)d_in[12];
    const float* bv    = (const float*)d_in[13];
    const float* W1    = (const float*)d_in[14];
    const float* b1    = (const float*)d_in[15];
    const float* W2    = (const float*)d_in[16];
    const float* b2    = (const float*)d_in[17];
    const float* Wmean = (const float*)d_in[18];
    const float* bmean = (const float*)d_in[19];
    const float* Wval  = (const float*)d_in[20];
    const float* bval  = (const float*)d_in[21];

    unsigned short* wf = (unsigned short*)d_ws;   // 158 frags * 64 lanes * 16 B

    conv_kernel<<<40, 256, 0, stream>>>(Wm, Wq, Wk, Wv, W1, W2, Wmean, Wval, wf);
    policy_kernel<<<512, 256, 0, stream>>>(seq, W_ih, W_hh, b_ih, b_hh, embed, wf,
                                           bm, bq, bk, bv, b1, b2, bmean, bval,
                                           (float*)d_out);
}

// Round 4
// 248.194 us; speedup vs baseline: 1.3506x; 1.0033x over previous
//
#include <hip/hip_runtime.h>

// Policy net fully fused: GRU(64 steps) -> comm-mean -> 8-agent attention -> MLP heads.
// K0: one-time weight->bf16 MFMA-fragment conversion into d_ws.
// K1: one wave = 16 seqs = 2 complete batches; GRU + ALL head phases wave-local
//     (zero __syncthreads). 2048 waves, waves_per_eu pinned to 2 (VGPR cap 256,
//     no spill — R3's 35 MB WRITE_SIZE was weight-fragment scratch spill at
//     VGPR_Count=128).

typedef float f32x4 __attribute__((ext_vector_type(4)));
typedef short bf16x8 __attribute__((ext_vector_type(8)));

#define MFMA16 __builtin_amdgcn_mfma_f32_16x16x32_bf16
#define LOG2E 1.44269504088896f
#define INV_SQRT_D 0.09449111825230679f

__device__ __forceinline__ short f2bf(float f) {          // RNE (cold paths)
    union { float f; unsigned u; } v; v.f = f;
    unsigned r = v.u + 0x7fffu + ((v.u >> 16) & 1u);
    return (short)(r >> 16);
}
__device__ __forceinline__ short f2bf_hu(float f) {       // round-half-up (hot paths)
    union { float f; unsigned u; } v; v.f = f;
    return (short)((v.u + 0x8000u) >> 16);
}
__device__ __forceinline__ float fexp2(float x) { return __builtin_amdgcn_exp2f(x); }
__device__ __forceinline__ float frcp(float x)  { return __builtin_amdgcn_rcpf(x); }
__device__ __forceinline__ void lds_fence() {             // cross-lane LDS RAW guard
    __asm__ __volatile__("s_waitcnt lgkmcnt(0)" ::: "memory");
}

// ---------------------------------------------------------------------------
// Kernel 0: head weights -> bf16 B-fragments (MFMA lane layout).
// fid: 0..5 Wm | 6..33 Wq | 34..61 Wk | 62..89 Wv | 90..121 W1 | 122..153 W2 |
//      154..157 heads.  Storage: wf[(fid*64+lane)*8 .. +7]
// ---------------------------------------------------------------------------
__global__ void conv_kernel(
    const float* __restrict__ Wm, const float* __restrict__ Wq,
    const float* __restrict__ Wk, const float* __restrict__ Wv,
    const float* __restrict__ W1, const float* __restrict__ W2,
    const float* __restrict__ Wmean, const float* __restrict__ Wval,
    unsigned short* __restrict__ wf)
{
    int gid = blockIdx.x * 256 + threadIdx.x;
    if (gid >= 158 * 64) return;
    int fid = gid >> 6, lane = gid & 63;
    int l15 = lane & 15, q = lane >> 4;

    short out[8] = {0,0,0,0,0,0,0,0};
    if (fid < 154) {
        const float* W; int nrows, Klim, idx;
        if (fid < 6)        { W = Wm; nrows = 32;  Klim = 80;  idx = fid;       }
        else if (fid < 34)  { W = Wq; nrows = 112; Klim = 112; idx = fid - 6;   }
        else if (fid < 62)  { W = Wk; nrows = 112; Klim = 112; idx = fid - 34;  }
        else if (fid < 90)  { W = Wv; nrows = 112; Klim = 112; idx = fid - 62;  }
        else if (fid < 122) { W = W1; nrows = 128; Klim = 112; idx = fid - 90;  }
        else                { W = W2; nrows = 128; Klim = 128; idx = fid - 122; }
        int nch = (fid < 6) ? 3 : 4;
        int ct = idx / nch, ch = idx - ct * nch;
        int g = ct * 16 + l15, k0 = ch * 32 + q * 8;
        if (g < nrows && (k0 + 8) <= Klim) {
            const float* wp = W + (size_t)g * Klim + k0;
            #pragma unroll
            for (int u = 0; u < 8; ++u) out[u] = f2bf(wp[u]);
        }
    } else {
        int ch = fid - 154, k0 = ch * 32 + q * 8;
        const float* wp = (l15 == 0) ? Wmean : (l15 == 1) ? (Wmean + 128)
                          : (l15 == 2) ? Wval : nullptr;
        if (wp) {
            #pragma unroll
            for (int u = 0; u < 8; ++u) out[u] = f2bf(wp[k0 + u]);
        }
    }
    *(bf16x8*)(wf + ((size_t)fid * 64 + lane) * 8) = *(bf16x8*)out;
}

// ---------------------------------------------------------------------------
// Kernel 1: fused policy. grid 512 x 256 -> 2048 waves x 16 seqs.
// ---------------------------------------------------------------------------
__global__ __launch_bounds__(256)
__attribute__((amdgpu_waves_per_eu(2, 2)))
void policy_kernel(
    const float* __restrict__ seq,    // [32768][64][4]
    const float* __restrict__ W_ih, const float* __restrict__ W_hh,
    const float* __restrict__ b_ih, const float* __restrict__ b_hh,
    const float* __restrict__ embed,
    const unsigned short* __restrict__ wf,
    const float* __restrict__ bm, const float* __restrict__ bq,
    const float* __restrict__ bk, const float* __restrict__ bv,
    const float* __restrict__ b1, const float* __restrict__ b2,
    const float* __restrict__ bmean, const float* __restrict__ bval,
    float* __restrict__ out)          // mean [32768][2] then val [32768]
{
    __shared__ short R1s[4][16][136];  // h(0..63)|id(64..79)|c(80..111)|pad -> O
    __shared__ short R2s[4][16][136];  // Q -> h3
    __shared__ short R3s[4][16][136];  // K -> h4
    __shared__ short Vts[4][114][20];  // V^T [Dcol][agent], zero-padded
    __shared__ short Pbs[4][16][40];   // attention probs (A-layout rows)

    const int tid  = threadIdx.x;
    const int wv   = tid >> 6;
    const int lane = tid & 63;
    const int l15  = lane & 15;
    const int q    = lane >> 4;
    const int seqbase = (blockIdx.x * 4 + wv) * 16;   // 16 seqs = 2 batches

    short (*R1)[136] = R1s[wv];
    short (*R2)[136] = R2s[wv];
    short (*R3)[136] = R3s[wv];
    short (*Vt)[20]  = Vts[wv];
    short (*Pb)[40]  = Pbs[wv];
    const f32x4 zz = {0.f, 0.f, 0.f, 0.f};

    {   // zero this wave's LDS slices (wave-local)
        int* p;
        p = (int*)&R1[0][0]; for (int i = lane; i < 1088; i += 64) p[i] = 0;
        p = (int*)&R2[0][0]; for (int i = lane; i < 1088; i += 64) p[i] = 0;
        p = (int*)&R3[0][0]; for (int i = lane; i < 1088; i += 64) p[i] = 0;
        p = (int*)&Vt[0][0]; for (int i = lane; i < 1140; i += 64) p[i] = 0;
        p = (int*)&Pb[0][0]; for (int i = lane; i < 320;  i += 64) p[i] = 0;
    }
    {   // id embedding -> R1 cols 64..79 (agent row i uses embed[i&7])
        int row = lane >> 2, j0 = (lane & 3) * 4;
        f32x4 e = *(const f32x4*)(embed + (row & 7) * 16 + j0);
        #pragma unroll
        for (int u = 0; u < 4; ++u) R1[row][64 + j0 + u] = f2bf(e[u]);
    }

    // ---- GRU weight fragments (pre-scaled so exps are exp2(acc) directly) ----
    // Bh[12][2]: W_hh (96 regs) | B2[8]: r,z x-proj + combined bias (32 regs)
    // B2x[4]: n-gate x-proj + b_ih_n (16 regs) | bhh_n[4]: b_hh_n scalars (VALU)
    const float sc_rz = -LOG2E;
    const float sc_n  = 2.0f * LOG2E;
    bf16x8 Bh[12][2], B2[8], B2x[4];
    float bhh_n[4];
    #pragma unroll
    for (int j = 0; j < 12; ++j) {
        int g = j * 16 + l15;
        float s = (j < 8) ? sc_rz : sc_n;
        #pragma unroll
        for (int c = 0; c < 2; ++c) {
            const float* wp = W_hh + g * 64 + c * 32 + q * 8;
            bf16x8 f;
            #pragma unroll
            for (int u = 0; u < 8; ++u) f[u] = f2bf(wp[u] * s);
            Bh[j][c] = f;
        }
    }
    #pragma unroll
    for (int j = 0; j < 8; ++j) {
        int g = j * 16 + l15;
        bf16x8 f2 = {0,0,0,0,0,0,0,0};
        if (q == 0) {
            #pragma unroll
            for (int u = 0; u < 4; ++u) f2[u] = f2bf(W_ih[g * 4 + u] * sc_rz);
            f2[4] = f2bf((b_ih[g] + b_hh[g]) * sc_rz);
        }
        B2[j] = f2;
    }
    #pragma unroll
    for (int j2 = 0; j2 < 4; ++j2) {
        int g = 128 + j2 * 16 + l15;
        bf16x8 f = {0,0,0,0,0,0,0,0};
        if (q == 0) {
            #pragma unroll
            for (int u = 0; u < 4; ++u) f[u] = f2bf(W_ih[g * 4 + u] * sc_n);
            f[4] = f2bf(b_ih[g] * sc_n);
        }
        B2x[j2] = f;
        bhh_n[j2] = b_hh[g] * sc_n;
    }
    lds_fence();

    // ---- GRU main loop: h lives in R1 cols 0..63 ----
    const short onebf = 0x3f80;
    float h[4][4];
    #pragma unroll
    for (int j = 0; j < 4; ++j)
        #pragma unroll
        for (int r = 0; r < 4; ++r) h[j][r] = 0.f;

    f32x4 xc = *(const f32x4*)(seq + (size_t)(seqbase + l15) * 256);

    for (int t = 0; t < 64; ++t) {
        int tn = (t < 63) ? t + 1 : 63;
        f32x4 xnext = *(const f32x4*)(seq + (size_t)(seqbase + l15) * 256 + tn * 4);

        bf16x8 A0 = *(const bf16x8*)&R1[l15][q * 8];
        bf16x8 A1 = *(const bf16x8*)&R1[l15][32 + q * 8];
        bf16x8 A2;
        A2[0] = f2bf_hu(xc[0]); A2[1] = f2bf_hu(xc[1]);
        A2[2] = f2bf_hu(xc[2]); A2[3] = f2bf_hu(xc[3]);
        A2[4] = onebf; A2[5] = 0; A2[6] = 0; A2[7] = 0;

        #pragma unroll
        for (int j = 0; j < 4; ++j) {
            f32x4 ar = MFMA16(A2, B2[j], zz, 0, 0, 0);
            ar = MFMA16(A0, Bh[j][0], ar, 0, 0, 0);
            ar = MFMA16(A1, Bh[j][1], ar, 0, 0, 0);
            f32x4 az = MFMA16(A2, B2[4 + j], zz, 0, 0, 0);
            az = MFMA16(A0, Bh[4 + j][0], az, 0, 0, 0);
            az = MFMA16(A1, Bh[4 + j][1], az, 0, 0, 0);
            f32x4 an = MFMA16(A0, Bh[8 + j][0], zz, 0, 0, 0);
            an = MFMA16(A1, Bh[8 + j][1], an, 0, 0, 0);
            f32x4 ax = MFMA16(A2, B2x[j], zz, 0, 0, 0);

            #pragma unroll
            for (int r = 0; r < 4; ++r) {
                float e_r  = fexp2(ar[r]);                 // exp(-pre_r)
                float rg   = frcp(1.f + e_r);
                float e_z  = fexp2(az[r]);                 // exp(-pre_z)
                float anb  = an[r] + bhh_n[j];             // 2log2e * hn
                float npre = fmaf(rg, anb, ax[r]);         // 2log2e*(xn + r*hn)
                float e_t  = fexp2(npre);
                float tp   = e_t + 1.f;
                float tm   = e_t - 1.f;
                float hv   = h[j][r];
                float num  = fmaf(hv, tp, e_z * tm);
                float den  = fmaf(tp, e_z, tp);
                float hnew = num * frcp(den);
                h[j][r] = hnew;
                R1[q * 4 + r][16 * j + l15] = f2bf_hu(hnew);
            }
        }
        xc = xnext;
    }
    lds_fence();

    // ---- head phases, all wave-local ----
    auto ld = [&](int fid) -> bf16x8 {
        return *(const bf16x8*)(wf + ((size_t)fid * 64 + lane) * 8);
    };

    // P1+P2: msgs = [h|id] @ Wm^T ; comm mean over own batch; c -> R1 cols 80..111
    #pragma unroll
    for (int ct = 0; ct < 2; ++ct) {
        f32x4 acc = zz;
        #pragma unroll
        for (int ch = 0; ch < 3; ++ch) {
            bf16x8 a = *(const bf16x8*)&R1[l15][ch * 32 + q * 8];
            acc = MFMA16(a, ld(ct * 3 + ch), acc, 0, 0, 0);
        }
        float s = acc[0] + acc[1] + acc[2] + acc[3];   // rows q*4..q*4+3
        s += __shfl_xor(s, 16, 64);                    // + other q of same batch
        float cv = 0.125f * s + bm[16 * ct + l15];
        short cb = f2bf_hu(cv);
        #pragma unroll
        for (int r = 0; r < 4; ++r) R1[q * 4 + r][80 + 16 * ct + l15] = cb;
    }
    lds_fence();

    // P3: Q,K,V (K=112 pad 128); Q pre-scaled; V stored transposed
    #pragma unroll
    for (int ct = 0; ct < 7; ++ct) {
        f32x4 aq = zz, ak = zz, av = zz;
        #pragma unroll
        for (int ch = 0; ch < 4; ++ch) {
            bf16x8 a = *(const bf16x8*)&R1[l15][ch * 32 + q * 8];
            aq = MFMA16(a, ld(6  + ct * 4 + ch), aq, 0, 0, 0);
            ak = MFMA16(a, ld(34 + ct * 4 + ch), ak, 0, 0, 0);
            av = MFMA16(a, ld(62 + ct * 4 + ch), av, 0, 0, 0);
        }
        int col = 16 * ct + l15;
        float biq = bq[col], bik = bk[col], biv = bv[col];
        #pragma unroll
        for (int r = 0; r < 4; ++r) {
            int row = q * 4 + r;
            R2[row][col] = f2bf_hu((aq[r] + biq) * INV_SQRT_D);
            R3[row][col] = f2bf_hu(ak[r] + bik);
            Vt[col][row] = f2bf_hu(av[r] + biv);
        }
    }
    lds_fence();

    // P4: S = Q K^T (16x16 = 2 batches block-diagonal); 8-wide softmax via shfl
    {
        f32x4 acc = zz;
        #pragma unroll
        for (int ch = 0; ch < 4; ++ch) {
            bf16x8 a = *(const bf16x8*)&R2[l15][ch * 32 + q * 8];
            bf16x8 b = *(const bf16x8*)&R3[l15][ch * 32 + q * 8];
            acc = MFMA16(a, b, acc, 0, 0, 0);
        }
        bool collow = (l15 < 8);
        #pragma unroll
        for (int r = 0; r < 4; ++r) {
            int rl = q * 4 + r;
            bool valid = ((rl < 8) == collow);
            float v = acc[r];
            float m = v;
            m = fmaxf(m, __shfl_xor(m, 1, 64));
            m = fmaxf(m, __shfl_xor(m, 2, 64));
            m = fmaxf(m, __shfl_xor(m, 4, 64));
            float e = fexp2(LOG2E * (v - m));
            float s = e;
            s += __shfl_xor(s, 1, 64);
            s += __shfl_xor(s, 2, 64);
            s += __shfl_xor(s, 4, 64);
            float pv = valid ? e * frcp(s) : 0.f;
            Pb[rl][l15] = f2bf_hu(pv);
        }
    }
    lds_fence();

    // P5: O = P V (K=32; P cols 16..31 zero) -> R1
    {
        bf16x8 a = *(const bf16x8*)&Pb[l15][q * 8];
        #pragma unroll
        for (int ct = 0; ct < 7; ++ct) {
            bf16x8 b = *(const bf16x8*)&Vt[16 * ct + l15][q * 8];
            f32x4 acc = MFMA16(a, b, zz, 0, 0, 0);
            #pragma unroll
            for (int r = 0; r < 4; ++r) R1[q * 4 + r][16 * ct + l15] = f2bf_hu(acc[r]);
        }
    }
    lds_fence();

    // P6: h3 = relu(O @ W1^T + b1)  K=112 pad 128 -> R2
    #pragma unroll
    for (int ct = 0; ct < 8; ++ct) {
        f32x4 acc = zz;
        #pragma unroll
        for (int ch = 0; ch < 4; ++ch) {
            bf16x8 a = *(const bf16x8*)&R1[l15][ch * 32 + q * 8];
            acc = MFMA16(a, ld(90 + ct * 4 + ch), acc, 0, 0, 0);
        }
        float bias = b1[16 * ct + l15];
        #pragma unroll
        for (int r = 0; r < 4; ++r)
            R2[q * 4 + r][16 * ct + l15] = f2bf_hu(fmaxf(acc[r] + bias, 0.f));
    }
    lds_fence();

    // P7: h4 = relu(h3 @ W2^T + b2)  K=128 -> R3
    #pragma unroll
    for (int ct = 0; ct < 8; ++ct) {
        f32x4 acc = zz;
        #pragma unroll
        for (int ch = 0; ch < 4; ++ch) {
            bf16x8 a = *(const bf16x8*)&R2[l15][ch * 32 + q * 8];
            acc = MFMA16(a, ld(122 + ct * 4 + ch), acc, 0, 0, 0);
        }
        float bias = b2[16 * ct + l15];
        #pragma unroll
        for (int r = 0; r < 4; ++r)
            R3[q * 4 + r][16 * ct + l15] = f2bf_hu(fmaxf(acc[r] + bias, 0.f));
    }
    lds_fence();

    // P8: heads (K=128): cols 0,1 -> mean; col 2 -> value
    {
        f32x4 acc = zz;
        #pragma unroll
        for (int ch = 0; ch < 4; ++ch) {
            bf16x8 a = *(const bf16x8*)&R3[l15][ch * 32 + q * 8];
            acc = MFMA16(a, ld(154 + ch), acc, 0, 0, 0);
        }
        if (l15 < 3) {
            float bias = (l15 == 0) ? bmean[0] : (l15 == 1) ? bmean[1] : bval[0];
            #pragma unroll
            for (int r = 0; r < 4; ++r) {
                int A = seqbase + q * 4 + r;
                float v = acc[r] + bias;
                if (l15 < 2) out[(size_t)A * 2 + l15] = v;
                else         out[65536 + A] = v;
            }
        }
    }
}

// ---------------------------------------------------------------------------
extern "C" void kernel_launch(void* const* d_in, const int* in_sizes, int n_in,
                              void* d_out, int out_size, void* d_ws, size_t ws_size,
                              hipStream_t stream) {
    const float* seq   = (const float*)d_in[0];
    const float* W_ih  = (const float*)d_in[1];
    const float* W_hh  = (const float*)d_in[2];
    const float* b_ih  = (const float*)d_in[3];
    const float* b_hh  = (const float*)d_in[4];
    const float* embed = (const float*)d_in[5];
    const float* Wm    = (const float*)d_in[6];
    const float* bm    = (const float*)d_in[7];
    const float* Wq    = (const float*)d_in[8];
    const float* bq    = (const float*)d_in[9];
    const float* Wk    = (const float*)d_in[10];
    const float* bk    = (const float*)d_in[11];
    const float* Wv    = (const float*)d_in[12];
    const float* bv    = (const float*)d_in[13];
    const float* W1    = (const float*)d_in[14];
    const float* b1    = (const float*)d_in[15];
    const float* W2    = (const float*)d_in[16];
    const float* b2    = (const float*)d_in[17];
    const float* Wmean = (const float*)d_in[18];
    const float* bmean = (const float*)d_in[19];
    const float* Wval  = (const float*)d_in[20];
    const float* bval  = (const float*)d_in[21];

    unsigned short* wf = (unsigned short*)d_ws;   // 158 frags * 64 lanes * 16 B

    conv_kernel<<<40, 256, 0, stream>>>(Wm, Wq, Wk, Wv, W1, W2, Wmean, Wval, wf);
    policy_kernel<<<512, 256, 0, stream>>>(seq, W_ih, W_hh, b_ih, b_hh, embed, wf,
                                           bm, bq, bk, bv, b1, b2, bmean, bval,
                                           (float*)d_out);
}